// Round 1
// baseline (334.565 us; speedup 1.0000x reference)
//
#include <hip/hip_runtime.h>

#define B_ 4
#define S_ 2048
#define H_ 1024

typedef __bf16 bf16x8 __attribute__((ext_vector_type(8)));
typedef float  f32x4  __attribute__((ext_vector_type(4)));

// round-to-nearest-even f32 -> bf16 bits
__device__ __forceinline__ unsigned short f2bf(float f) {
  unsigned u = __float_as_uint(f);
  u += 0x7FFF + ((u >> 16) & 1);
  return (unsigned short)(u >> 16);
}

// ---------------------------------------------------------------- convert
__global__ void cvt_kernel(const float* __restrict__ in,
                           unsigned short* __restrict__ out, int n4) {
  int i = blockIdx.x * blockDim.x + threadIdx.x;
  if (i >= n4) return;
  const float4 v = reinterpret_cast<const float4*>(in)[i];
  ushort4 o;
  o.x = f2bf(v.x); o.y = f2bf(v.y); o.z = f2bf(v.z); o.w = f2bf(v.w);
  reinterpret_cast<ushort4*>(out)[i] = o;
}

// ---------------------------------------------------------------- GEMM core
// Tile: BM=BN=128, BK=64. 4 waves (2x2), each wave -> 64x64 out (4x4 frags).
// LDS layout: [row][128B of K] with T2 XOR-swizzle byte ^= (row&7)<<4,
// applied on the GLOBAL source address (global_load_lds writes linearly)
// and on the ds_read address (same involution) -> 2-way conflicts only.
__device__ __forceinline__ void stage_tile(const unsigned short* __restrict__ g,
                                           long row0, long ld, long k0,
                                           char* s, int t) {
  int wave = t >> 6;
#pragma unroll
  for (int i = 0; i < 4; ++i) {
    int ci  = i * 256 + t;        // 16B chunk id 0..1023
    int off = ci << 4;            // byte in 16KB tile
    int r   = off >> 7;           // row 0..127
    int o   = off & 127;          // byte within row
    int osw = o ^ ((r & 7) << 4); // pre-swizzled source byte
    const char* gp = reinterpret_cast<const char*>(g + (row0 + r) * ld + k0) + osw;
    char* lp = s + ((i * 256 + wave * 64) << 4);  // wave-uniform LDS base
    __builtin_amdgcn_global_load_lds((const __attribute__((address_space(1))) void*)gp,
                                     (__attribute__((address_space(3))) void*)lp,
                                     16, 0, 0);
  }
}

template <int KSTEPS>
__device__ __forceinline__ void gemm_loop(const unsigned short* __restrict__ A, long ldA, long m0,
                                          const unsigned short* __restrict__ Bm, long ldB, long n0,
                                          char* smem, f32x4 acc[4][4]) {
  const int t    = threadIdx.x;
  const int lane = t & 63;
  const int wr   = (t >> 7) & 1;
  const int wc   = (t >> 6) & 1;
  char* sA = smem;
  char* sB = smem + 16384;
  for (int kt = 0; kt < KSTEPS; ++kt) {
    __syncthreads();                       // previous compute done
    stage_tile(A,  m0, ldA, (long)kt * 64, sA, t);
    stage_tile(Bm, n0, ldB, (long)kt * 64, sB, t);
    __syncthreads();                       // vmcnt drain + barrier
#pragma unroll
    for (int ks = 0; ks < 2; ++ks) {
      bf16x8 af[4], bfr[4];
      const int kb = ks * 64 + (lane >> 4) * 16;
#pragma unroll
      for (int mf = 0; mf < 4; ++mf) {
        int row = wr * 64 + mf * 16 + (lane & 15);
        af[mf] = *reinterpret_cast<const bf16x8*>(sA + row * 128 + (kb ^ ((row & 7) << 4)));
      }
#pragma unroll
      for (int nf = 0; nf < 4; ++nf) {
        int row = wc * 64 + nf * 16 + (lane & 15);
        bfr[nf] = *reinterpret_cast<const bf16x8*>(sB + row * 128 + (kb ^ ((row & 7) << 4)));
      }
#pragma unroll
      for (int mf = 0; mf < 4; ++mf)
#pragma unroll
        for (int nf = 0; nf < 4; ++nf)
          acc[mf][nf] = __builtin_amdgcn_mfma_f32_16x16x32_bf16(af[mf], bfr[nf], acc[mf][nf], 0, 0, 0);
    }
  }
}

// ---------------------------------------------------------------- QKV projection
// out = x @ W^T + b ; grid.z selects (Wq,bq,Q)/(Wk,bk,K)/(Wv,bv,V)
__global__ __launch_bounds__(256) void qkv_kernel(
    const unsigned short* __restrict__ x, const unsigned short* __restrict__ W3,
    const float* __restrict__ bq, const float* __restrict__ bk, const float* __restrict__ bv,
    unsigned short* __restrict__ Q, unsigned short* __restrict__ K, unsigned short* __restrict__ V) {
  __shared__ char smem[32768];
  const int z = blockIdx.z;
  const unsigned short* W = W3 + (size_t)z * (H_ * H_);
  const float* bias = (z == 0) ? bq : (z == 1) ? bk : bv;
  unsigned short* out = (z == 0) ? Q : (z == 1) ? K : V;
  const long m0 = (long)blockIdx.y * 128, n0 = (long)blockIdx.x * 128;
  f32x4 acc[4][4] = {};
  gemm_loop<H_ / 64>(x, H_, m0, W, H_, n0, smem, acc);
  const int lane = threadIdx.x & 63;
  const int wr = (threadIdx.x >> 7) & 1, wc = (threadIdx.x >> 6) & 1;
#pragma unroll
  for (int nf = 0; nf < 4; ++nf) {
    long col = n0 + wc * 64 + nf * 16 + (lane & 15);
    float bb = bias[col];
#pragma unroll
    for (int mf = 0; mf < 4; ++mf)
#pragma unroll
      for (int r = 0; r < 4; ++r) {
        long row = m0 + wr * 64 + mf * 16 + (lane >> 4) * 4 + r;
        out[row * H_ + col] = f2bf(acc[mf][nf][r] + bb);
      }
  }
}

// ---------------------------------------------------------------- V transpose
// V [B][S][H] -> VT [B][H][S]  (so PV's B-operand is in natural B^T layout)
__global__ void vtrans_kernel(const unsigned short* __restrict__ V,
                              unsigned short* __restrict__ VT) {
  __shared__ unsigned short tile[64][66];
  const int b = blockIdx.z;
  const int c0 = blockIdx.x * 64;  // H
  const int r0 = blockIdx.y * 64;  // S
  const int tx = threadIdx.x, ty = threadIdx.y;
  const unsigned short* Vb = V + (size_t)b * S_ * H_;
  unsigned short* VTb = VT + (size_t)b * H_ * S_;
#pragma unroll
  for (int i = 0; i < 16; ++i) {
    int r = ty * 16 + i;
    tile[r][tx] = Vb[(size_t)(r0 + r) * H_ + c0 + tx];
  }
  __syncthreads();
#pragma unroll
  for (int i = 0; i < 16; ++i) {
    int c = ty * 16 + i;
    VTb[(size_t)(c0 + c) * S_ + r0 + tx] = tile[tx][c];
  }
}

// ---------------------------------------------------------------- scores = QK^T
// Epilogue: mask -> p = exp(s/32) or 0 (mask fill -1e9 pre-scale == exact 0),
// no max-subtraction (|s/32| bounded ~4), P in bf16, fp32 rowsum via atomics.
__global__ __launch_bounds__(256) void scores_kernel(
    const unsigned short* __restrict__ Q, const unsigned short* __restrict__ Km,
    const int* __restrict__ mask, unsigned short* __restrict__ P,
    float* __restrict__ rowsum) {
  __shared__ char smem[32768];
  const int b = blockIdx.z;
  const long m0 = (long)blockIdx.y * 128, n0 = (long)blockIdx.x * 128;
  const unsigned short* Qb = Q + (size_t)b * S_ * H_;
  const unsigned short* Kb = Km + (size_t)b * S_ * H_;
  const int* Mb = mask + (size_t)b * S_ * S_;
  unsigned short* Pb = P + (size_t)b * S_ * S_;
  f32x4 acc[4][4] = {};
  gemm_loop<H_ / 64>(Qb, H_, m0, Kb, H_, n0, smem, acc);
  const int lane = threadIdx.x & 63;
  const int wr = (threadIdx.x >> 7) & 1, wc = (threadIdx.x >> 6) & 1;
#pragma unroll
  for (int mf = 0; mf < 4; ++mf) {
#pragma unroll
    for (int r = 0; r < 4; ++r) {
      long row = m0 + wr * 64 + mf * 16 + (lane >> 4) * 4 + r;
      float rs = 0.f;
#pragma unroll
      for (int nf = 0; nf < 4; ++nf) {
        long col = n0 + wc * 64 + nf * 16 + (lane & 15);
        float p = Mb[row * S_ + col] ? __expf(acc[mf][nf][r] * 0.03125f) : 0.f;
        Pb[row * S_ + col] = f2bf(p);
        rs += p;
      }
#pragma unroll
      for (int s = 1; s < 16; s <<= 1) rs += __shfl_xor(rs, s, 64);
      if ((lane & 15) == 0) atomicAdd(&rowsum[(size_t)b * S_ + row], rs);
    }
  }
}

// ---------------------------------------------------------------- out = (P V) / rowsum
__global__ __launch_bounds__(256) void pv_kernel(
    const unsigned short* __restrict__ P, const unsigned short* __restrict__ VT,
    const float* __restrict__ rowsum, float* __restrict__ out) {
  __shared__ char smem[32768];
  const int b = blockIdx.z;
  const long m0 = (long)blockIdx.y * 128, n0 = (long)blockIdx.x * 128;
  const unsigned short* Pb = P + (size_t)b * S_ * S_;
  const unsigned short* VTb = VT + (size_t)b * H_ * S_;
  f32x4 acc[4][4] = {};
  gemm_loop<S_ / 64>(Pb, S_, m0, VTb, S_, n0, smem, acc);
  const int lane = threadIdx.x & 63;
  const int wr = (threadIdx.x >> 7) & 1, wc = (threadIdx.x >> 6) & 1;
#pragma unroll
  for (int mf = 0; mf < 4; ++mf)
#pragma unroll
    for (int r = 0; r < 4; ++r) {
      long row = m0 + wr * 64 + mf * 16 + (lane >> 4) * 4 + r;
      float inv = 1.f / rowsum[(size_t)b * S_ + row];
#pragma unroll
      for (int nf = 0; nf < 4; ++nf) {
        long col = n0 + wc * 64 + nf * 16 + (lane & 15);
        out[((size_t)b * S_ + row) * H_ + col] = acc[mf][nf][r] * inv;
      }
    }
}

// ---------------------------------------------------------------- launch
extern "C" void kernel_launch(void* const* d_in, const int* in_sizes, int n_in,
                              void* d_out, int out_size, void* d_ws, size_t ws_size,
                              hipStream_t stream) {
  const float* x   = (const float*)d_in[0];
  const int* mask  = (const int*)d_in[1];
  const float* Wq  = (const float*)d_in[2];
  const float* bq  = (const float*)d_in[3];
  const float* Wk  = (const float*)d_in[4];
  const float* bk  = (const float*)d_in[5];
  const float* Wv  = (const float*)d_in[6];
  const float* bv  = (const float*)d_in[7];
  float* out = (float*)d_out;

  const size_t MS = (size_t)B_ * S_ * H_;  // 8388608
  unsigned short* xb  = (unsigned short*)d_ws;           // x in bf16
  unsigned short* W3  = xb + MS;                         // Wq|Wk|Wv bf16
  unsigned short* Qb  = W3 + (size_t)3 * H_ * H_;
  unsigned short* Kb  = Qb + MS;
  unsigned short* Vb  = Kb + MS;
  unsigned short* VTb = Vb + MS;
  unsigned short* Pb  = VTb + MS;                        // B*S*S bf16
  float* rowsum = (float*)(Pb + (size_t)B_ * S_ * S_);   // B*S fp32
  // total ws use ~124 MB

  hipMemsetAsync(rowsum, 0, (size_t)B_ * S_ * sizeof(float), stream);

  cvt_kernel<<<(int)(MS / 4 / 256), 256, 0, stream>>>(x, xb, (int)(MS / 4));
  cvt_kernel<<<H_ * H_ / 4 / 256, 256, 0, stream>>>(Wq, W3, H_ * H_ / 4);
  cvt_kernel<<<H_ * H_ / 4 / 256, 256, 0, stream>>>(Wk, W3 + H_ * H_, H_ * H_ / 4);
  cvt_kernel<<<H_ * H_ / 4 / 256, 256, 0, stream>>>(Wv, W3 + 2 * H_ * H_, H_ * H_ / 4);

  qkv_kernel<<<dim3(H_ / 128, (B_ * S_) / 128, 3), 256, 0, stream>>>(
      xb, W3, bq, bk, bv, Qb, Kb, Vb);

  vtrans_kernel<<<dim3(H_ / 64, S_ / 64, B_), dim3(64, 4), 0, stream>>>(Vb, VTb);

  scores_kernel<<<dim3(S_ / 128, S_ / 128, B_), 256, 0, stream>>>(
      Qb, Kb, mask, Pb, rowsum);

  pv_kernel<<<dim3(H_ / 128, S_ / 128, B_), 256, 0, stream>>>(Pb, VTb, rowsum, out);
}

// Round 2
// 324.257 us; speedup vs baseline: 1.0318x; 1.0318x over previous
//
#include <hip/hip_runtime.h>

#define B_ 4
#define S_ 2048
#define H_ 1024

typedef __bf16 bf16x8 __attribute__((ext_vector_type(8)));
typedef float  f32x4  __attribute__((ext_vector_type(4)));

__device__ __forceinline__ unsigned short f2bf(float f) {
  unsigned u = __float_as_uint(f);
  u += 0x7FFF + ((u >> 16) & 1);
  return (unsigned short)(u >> 16);
}

// ---------------- fused fp32->bf16 convert (x | Wq | Wk | Wv contiguous) ----
__global__ void cvt_all_kernel(const float* __restrict__ x,
                               const float* __restrict__ wq,
                               const float* __restrict__ wk,
                               const float* __restrict__ wv,
                               unsigned short* __restrict__ dst) {
  int i = blockIdx.x * blockDim.x + threadIdx.x;  // float4 index
  const int NX = (B_ * S_ * H_) / 4;
  const int NW = (H_ * H_) / 4;
  const float* src; int off;
  if (i < NX) { src = x; off = i; }
  else { int j = i - NX; int w = j >> 18; off = j & (NW - 1);
         src = (w == 0) ? wq : (w == 1) ? wk : wv; }
  float4 v = reinterpret_cast<const float4*>(src)[off];
  ushort4 o; o.x = f2bf(v.x); o.y = f2bf(v.y); o.z = f2bf(v.z); o.w = f2bf(v.w);
  reinterpret_cast<ushort4*>(dst)[i] = o;
}

// ---------------- 256x256 8-phase GEMM core --------------------------------
// 512 threads = 8 waves (2M x 4N). Per-wave out 128x64 (acc[8][4]).
// LDS 128 KiB: sA0|sB0|sA1|sB1, each 256x64 bf16 (32 KiB), rows of 128 B with
// XOR swizzle byte ^= (row&7)<<4 (applied on pre-swizzled global source for
// global_load_lds linear dest, and on the ds_read address — same involution).
// Per K-tile: 4 phases (one 32-row quadrant x K=64 = 16 MFMA each).
// Staging (quarter-tiles, 2 loads/phase): during kt's phases stage
//   P1: A-q1,q3(kt+1)->other buf; P2: B-q0,q1(kt+2)->this buf;
//   P3: B-q2,q3(kt+2);            P4: A-q0,q2(kt+2) + s_waitcnt vmcnt(6).
// Safety: a region staged at phase p was last read at phase <= p-1, whose
// ds_reads complete (lgkmcnt 0) before that phase's closing s_barrier, which
// precedes the stage issue. vmcnt(6)+barrier at P4 makes everything except
// the newest 3 phases' loads (6) visible before the next K-tile reads it.

__device__ __forceinline__ bf16x8 lfrag(const char* base, int row, int kb) {
  return *reinterpret_cast<const bf16x8*>(base + row * 128 + (kb ^ ((row & 7) << 4)));
}

__device__ __forceinline__ void stage_q(const unsigned short* __restrict__ g,
                                        long row0, long ld, int k0e,
                                        char* sbase, int q, int t) {
  int row = q * 64 + (t >> 3);
  int osw = ((t & 7) << 4) ^ ((row & 7) << 4);
  const char* gp = reinterpret_cast<const char*>(g + (row0 + row) * ld + k0e) + osw;
  char* lp = sbase + q * 8192 + ((t >> 6) << 10);  // wave-uniform; HW adds lane*16
  __builtin_amdgcn_global_load_lds((const __attribute__((address_space(1))) void*)gp,
                                   (__attribute__((address_space(3))) void*)lp,
                                   16, 0, 0);
}

template <int NT>
__device__ __forceinline__ void gemm8(const unsigned short* __restrict__ A, long ldA, long m0,
                                      const unsigned short* __restrict__ Bm, long ldB, long n0,
                                      char* sm, f32x4 acc[8][4]) {
  const int t = threadIdx.x;
  const int lane = t & 63;
  const int wid = t >> 6;
  const int wr = wid >> 2, wc = wid & 3;
  const int lrow = lane & 15;
  const int kb0 = (lane >> 4) * 16;
  char* sA0 = sm;          char* sB0 = sm + 32768;
  char* sA1 = sm + 65536;  char* sB1 = sm + 98304;

  // prologue: kt0 full (8 loads) + kt1 partial B01,B23,Aq0,Aq2 (6 loads)
#pragma unroll
  for (int q = 0; q < 4; ++q) stage_q(A, m0, ldA, 0, sA0, q, t);
#pragma unroll
  for (int q = 0; q < 4; ++q) stage_q(Bm, n0, ldB, 0, sB0, q, t);
#pragma unroll
  for (int q = 0; q < 4; ++q) stage_q(Bm, n0, ldB, 64, sB1, q, t);
  stage_q(A, m0, ldA, 64, sA1, 0, t);
  stage_q(A, m0, ldA, 64, sA1, 2, t);
  asm volatile("s_waitcnt vmcnt(6)" ::: "memory");  // kt0's 8 drained
  __builtin_amdgcn_s_barrier();

  auto ktile = [&](int kt, char* cA, char* cB, char* nA) {
    const int k1 = (kt + 1 < NT ? kt + 1 : NT - 1) * 64;
    const int k2 = (kt + 2 < NT ? kt + 2 : NT - 1) * 64;
    bf16x8 bfr[4][2], af[2][2];
    // ---- P1 (q=0): read all B + A-q0; stage A-q1,q3(kt+1)
#pragma unroll
    for (int nf = 0; nf < 4; ++nf)
#pragma unroll
      for (int ks = 0; ks < 2; ++ks)
        bfr[nf][ks] = lfrag(cB, wc * 64 + nf * 16 + lrow, ks * 64 + kb0);
#pragma unroll
    for (int mf = 0; mf < 2; ++mf)
#pragma unroll
      for (int ks = 0; ks < 2; ++ks)
        af[mf][ks] = lfrag(cA, wr * 128 + mf * 16 + lrow, ks * 64 + kb0);
    stage_q(A, m0, ldA, k1, nA, 1, t);
    stage_q(A, m0, ldA, k1, nA, 3, t);
    __builtin_amdgcn_s_barrier();
    asm volatile("s_waitcnt lgkmcnt(0)" ::: "memory");
    __builtin_amdgcn_sched_barrier(0);
    __builtin_amdgcn_s_setprio(1);
#pragma unroll
    for (int mf = 0; mf < 2; ++mf)
#pragma unroll
      for (int nf = 0; nf < 4; ++nf)
#pragma unroll
        for (int ks = 0; ks < 2; ++ks)
          acc[mf][nf] = __builtin_amdgcn_mfma_f32_16x16x32_bf16(af[mf][ks], bfr[nf][ks], acc[mf][nf], 0, 0, 0);
    __builtin_amdgcn_s_setprio(0);
    __builtin_amdgcn_s_barrier();
    // ---- P2..P4 (q=1..3)
#pragma unroll
    for (int q = 1; q < 4; ++q) {
#pragma unroll
      for (int mf = 0; mf < 2; ++mf)
#pragma unroll
        for (int ks = 0; ks < 2; ++ks)
          af[mf][ks] = lfrag(cA, wr * 128 + q * 32 + mf * 16 + lrow, ks * 64 + kb0);
      if (q == 1) { stage_q(Bm, n0, ldB, k2, cB, 0, t); stage_q(Bm, n0, ldB, k2, cB, 1, t); }
      if (q == 2) { stage_q(Bm, n0, ldB, k2, cB, 2, t); stage_q(Bm, n0, ldB, k2, cB, 3, t); }
      if (q == 3) { stage_q(A, m0, ldA, k2, cA, 0, t); stage_q(A, m0, ldA, k2, cA, 2, t);
                    asm volatile("s_waitcnt vmcnt(6)" ::: "memory"); }
      __builtin_amdgcn_s_barrier();
      asm volatile("s_waitcnt lgkmcnt(0)" ::: "memory");
      __builtin_amdgcn_sched_barrier(0);
      __builtin_amdgcn_s_setprio(1);
#pragma unroll
      for (int mf = 0; mf < 2; ++mf)
#pragma unroll
        for (int nf = 0; nf < 4; ++nf)
#pragma unroll
          for (int ks = 0; ks < 2; ++ks)
            acc[2 * q + mf][nf] = __builtin_amdgcn_mfma_f32_16x16x32_bf16(af[mf][ks], bfr[nf][ks], acc[2 * q + mf][nf], 0, 0, 0);
      __builtin_amdgcn_s_setprio(0);
      __builtin_amdgcn_s_barrier();
    }
  };

#pragma unroll 1
  for (int kt = 0; kt < NT; kt += 2) {
    ktile(kt,     sA0, sB0, sA1);
    ktile(kt + 1, sA1, sB1, sA0);
  }
}

// ---------------- QKV projection: out = x @ W^T + b -------------------------
__global__ __launch_bounds__(512, 2) void qkv_kernel(
    const unsigned short* __restrict__ x, const unsigned short* __restrict__ W3,
    const float* __restrict__ bq, const float* __restrict__ bk, const float* __restrict__ bv,
    unsigned short* __restrict__ Q, unsigned short* __restrict__ K, unsigned short* __restrict__ V) {
  extern __shared__ char sm[];
  const int z = blockIdx.z;
  const unsigned short* W = W3 + (size_t)z * (H_ * H_);
  const float* bias = (z == 0) ? bq : (z == 1) ? bk : bv;
  unsigned short* out = (z == 0) ? Q : (z == 1) ? K : V;
  const long m0 = (long)blockIdx.y * 256, n0 = (long)blockIdx.x * 256;
  f32x4 acc[8][4] = {};
  gemm8<H_ / 64>(x, H_, m0, W, H_, n0, sm, acc);
  const int lane = threadIdx.x & 63;
  const int wid = threadIdx.x >> 6;
  const int wr = wid >> 2, wc = wid & 3;
#pragma unroll
  for (int nf = 0; nf < 4; ++nf) {
    long col = n0 + wc * 64 + nf * 16 + (lane & 15);
    float bb = bias[col];
#pragma unroll
    for (int mq = 0; mq < 8; ++mq)
#pragma unroll
      for (int r = 0; r < 4; ++r) {
        long row = m0 + wr * 128 + mq * 16 + (lane >> 4) * 4 + r;
        out[row * H_ + col] = f2bf(acc[mq][nf][r] + bb);
      }
  }
}

// ---------------- V transpose [B][S][H] -> [B][H][S] ------------------------
__global__ void vtrans_kernel(const unsigned short* __restrict__ V,
                              unsigned short* __restrict__ VT) {
  __shared__ unsigned short tile[64][66];
  const int b = blockIdx.z;
  const int c0 = blockIdx.x * 64;  // H
  const int r0 = blockIdx.y * 64;  // S
  const int tx = threadIdx.x, ty = threadIdx.y;
  const unsigned short* Vb = V + (size_t)b * S_ * H_;
  unsigned short* VTb = VT + (size_t)b * H_ * S_;
#pragma unroll
  for (int i = 0; i < 16; ++i) {
    int r = ty * 16 + i;
    tile[r][tx] = Vb[(size_t)(r0 + r) * H_ + c0 + tx];
  }
  __syncthreads();
#pragma unroll
  for (int i = 0; i < 16; ++i) {
    int c = ty * 16 + i;
    VTb[(size_t)(c0 + c) * S_ + r0 + tx] = tile[tx][c];
  }
}

// ---------------- scores = QK^T -> masked exp -> P(bf16) + rowsum -----------
__global__ __launch_bounds__(512, 2) void scores_kernel(
    const unsigned short* __restrict__ Q, const unsigned short* __restrict__ Km,
    const int* __restrict__ mask, unsigned short* __restrict__ P,
    float* __restrict__ rowsum) {
  extern __shared__ char sm[];
  const int b = blockIdx.z;
  const long m0 = (long)blockIdx.y * 256, n0 = (long)blockIdx.x * 256;
  const unsigned short* Qb = Q + (size_t)b * S_ * H_;
  const unsigned short* Kb = Km + (size_t)b * S_ * H_;
  const int* Mb = mask + (size_t)b * S_ * S_;
  unsigned short* Pb = P + (size_t)b * S_ * S_;
  f32x4 acc[8][4] = {};
  gemm8<H_ / 64>(Qb, H_, m0, Kb, H_, n0, sm, acc);
  const int lane = threadIdx.x & 63;
  const int wid = threadIdx.x >> 6;
  const int wr = wid >> 2, wc = wid & 3;
#pragma unroll
  for (int mq = 0; mq < 8; ++mq) {
#pragma unroll
    for (int r = 0; r < 4; ++r) {
      long row = m0 + wr * 128 + mq * 16 + (lane >> 4) * 4 + r;
      float rs = 0.f;
#pragma unroll
      for (int nf = 0; nf < 4; ++nf) {
        long col = n0 + wc * 64 + nf * 16 + (lane & 15);
        float p = Mb[row * S_ + col] ? __expf(acc[mq][nf][r] * 0.03125f) : 0.f;
        Pb[row * S_ + col] = f2bf(p);
        rs += p;
      }
#pragma unroll
      for (int s = 1; s < 16; s <<= 1) rs += __shfl_xor(rs, s, 64);
      if ((lane & 15) == 0) atomicAdd(&rowsum[(size_t)b * S_ + row], rs);
    }
  }
}

// ---------------- out = (P V) / rowsum --------------------------------------
__global__ __launch_bounds__(512, 2) void pv_kernel(
    const unsigned short* __restrict__ P, const unsigned short* __restrict__ VT,
    const float* __restrict__ rowsum, float* __restrict__ out) {
  extern __shared__ char sm[];
  const int b = blockIdx.z;
  const long m0 = (long)blockIdx.y * 256, n0 = (long)blockIdx.x * 256;
  const unsigned short* Pb = P + (size_t)b * S_ * S_;
  const unsigned short* VTb = VT + (size_t)b * H_ * S_;
  f32x4 acc[8][4] = {};
  gemm8<S_ / 64>(Pb, S_, m0, VTb, S_, n0, sm, acc);
  const int lane = threadIdx.x & 63;
  const int wid = threadIdx.x >> 6;
  const int wr = wid >> 2, wc = wid & 3;
#pragma unroll
  for (int mq = 0; mq < 8; ++mq)
#pragma unroll
    for (int r = 0; r < 4; ++r) {
      long row = m0 + wr * 128 + mq * 16 + (lane >> 4) * 4 + r;
      float inv = 1.f / rowsum[(size_t)b * S_ + row];
#pragma unroll
      for (int nf = 0; nf < 4; ++nf) {
        long col = n0 + wc * 64 + nf * 16 + (lane & 15);
        out[((size_t)b * S_ + row) * H_ + col] = acc[mq][nf][r] * inv;
      }
    }
}

// ---------------- launch ----------------------------------------------------
extern "C" void kernel_launch(void* const* d_in, const int* in_sizes, int n_in,
                              void* d_out, int out_size, void* d_ws, size_t ws_size,
                              hipStream_t stream) {
  const float* x   = (const float*)d_in[0];
  const int* mask  = (const int*)d_in[1];
  const float* Wq  = (const float*)d_in[2];
  const float* bq  = (const float*)d_in[3];
  const float* Wk  = (const float*)d_in[4];
  const float* bk  = (const float*)d_in[5];
  const float* Wv  = (const float*)d_in[6];
  const float* bv  = (const float*)d_in[7];
  float* out = (float*)d_out;

  const size_t MS = (size_t)B_ * S_ * H_;
  unsigned short* xb  = (unsigned short*)d_ws;
  unsigned short* W3  = xb + MS;
  unsigned short* Qb  = W3 + (size_t)3 * H_ * H_;
  unsigned short* Kb  = Qb + MS;
  unsigned short* Vb  = Kb + MS;
  unsigned short* VTb = Vb + MS;
  unsigned short* Pb  = VTb + MS;
  float* rowsum = (float*)(Pb + (size_t)B_ * S_ * S_);

  (void)hipFuncSetAttribute(reinterpret_cast<const void*>(qkv_kernel),
                            hipFuncAttributeMaxDynamicSharedMemorySize, 131072);
  (void)hipFuncSetAttribute(reinterpret_cast<const void*>(scores_kernel),
                            hipFuncAttributeMaxDynamicSharedMemorySize, 131072);
  (void)hipFuncSetAttribute(reinterpret_cast<const void*>(pv_kernel),
                            hipFuncAttributeMaxDynamicSharedMemorySize, 131072);

  hipMemsetAsync(rowsum, 0, (size_t)B_ * S_ * sizeof(float), stream);

  const int NCVT = (int)(MS / 4) + 3 * (H_ * H_ / 4);
  cvt_all_kernel<<<NCVT / 256, 256, 0, stream>>>(x, Wq, Wk, Wv, xb);

  qkv_kernel<<<dim3(H_ / 256, (B_ * S_) / 256, 3), 512, 131072, stream>>>(
      xb, W3, bq, bk, bv, Qb, Kb, Vb);

  vtrans_kernel<<<dim3(H_ / 64, S_ / 64, B_), dim3(64, 4), 0, stream>>>(Vb, VTb);

  scores_kernel<<<dim3(S_ / 256, S_ / 256, B_), 512, 131072, stream>>>(
      Qb, Kb, mask, Pb, rowsum);

  pv_kernel<<<dim3(H_ / 256, S_ / 256, B_), 512, 131072, stream>>>(Pb, VTb, rowsum, out);
}

// Round 3
// 320.110 us; speedup vs baseline: 1.0452x; 1.0130x over previous
//
#include <hip/hip_runtime.h>

#define B_ 4
#define S_ 2048
#define H_ 1024

typedef __bf16 bf16x8 __attribute__((ext_vector_type(8)));
typedef float  f32x4  __attribute__((ext_vector_type(4)));
typedef short  short8 __attribute__((ext_vector_type(8)));

__device__ __forceinline__ unsigned short f2bf(float f) {
  unsigned u = __float_as_uint(f);
  u += 0x7FFF + ((u >> 16) & 1);
  return (unsigned short)(u >> 16);
}

// ---------------- fused fp32->bf16 convert (x | Wq | Wk | Wv contiguous) ----
__global__ void cvt_all_kernel(const float* __restrict__ x,
                               const float* __restrict__ wq,
                               const float* __restrict__ wk,
                               const float* __restrict__ wv,
                               unsigned short* __restrict__ dst) {
  int i = blockIdx.x * blockDim.x + threadIdx.x;  // float4 index
  const int NX = (B_ * S_ * H_) / 4;
  const int NW = (H_ * H_) / 4;
  const float* src; int off;
  if (i < NX) { src = x; off = i; }
  else { int j = i - NX; int w = j >> 18; off = j & (NW - 1);
         src = (w == 0) ? wq : (w == 1) ? wk : wv; }
  float4 v = reinterpret_cast<const float4*>(src)[off];
  ushort4 o; o.x = f2bf(v.x); o.y = f2bf(v.y); o.z = f2bf(v.z); o.w = f2bf(v.w);
  reinterpret_cast<ushort4*>(dst)[i] = o;
}

// ---------------- mask -> bit pack (64 MB int32 -> 8 MB bits) --------------
// word w of row r: bit l = (mask[r][64w+l] != 0)
__global__ void maskpack_kernel(const int* __restrict__ mask,
                                unsigned long long* __restrict__ mpk) {
  const int lane = threadIdx.x & 63;
  const long row = (long)blockIdx.x * 4 + (threadIdx.x >> 6);
  const int* mrow = mask + row * S_;
#pragma unroll
  for (int w = 0; w < S_ / 64; ++w) {
    int v = mrow[w * 64 + lane];
    unsigned long long b = __ballot(v != 0);
    if (lane == 0) mpk[row * (S_ / 64) + w] = b;
  }
}

// ---------------- 256x256 8-phase GEMM core (unchanged from R1) ------------
__device__ __forceinline__ bf16x8 lfrag(const char* base, int row, int kb) {
  return *reinterpret_cast<const bf16x8*>(base + row * 128 + (kb ^ ((row & 7) << 4)));
}

__device__ __forceinline__ void stage_q(const unsigned short* __restrict__ g,
                                        long row0, long ld, int k0e,
                                        char* sbase, int q, int t) {
  int row = q * 64 + (t >> 3);
  int osw = ((t & 7) << 4) ^ ((row & 7) << 4);
  const char* gp = reinterpret_cast<const char*>(g + (row0 + row) * ld + k0e) + osw;
  char* lp = sbase + q * 8192 + ((t >> 6) << 10);  // wave-uniform; HW adds lane*16
  __builtin_amdgcn_global_load_lds((const __attribute__((address_space(1))) void*)gp,
                                   (__attribute__((address_space(3))) void*)lp,
                                   16, 0, 0);
}

template <int NT>
__device__ __forceinline__ void gemm8(const unsigned short* __restrict__ A, long ldA, long m0,
                                      const unsigned short* __restrict__ Bm, long ldB, long n0,
                                      char* sm, f32x4 acc[8][4]) {
  const int t = threadIdx.x;
  const int lane = t & 63;
  const int wid = t >> 6;
  const int wr = wid >> 2, wc = wid & 3;
  const int lrow = lane & 15;
  const int kb0 = (lane >> 4) * 16;
  char* sA0 = sm;          char* sB0 = sm + 32768;
  char* sA1 = sm + 65536;  char* sB1 = sm + 98304;

#pragma unroll
  for (int q = 0; q < 4; ++q) stage_q(A, m0, ldA, 0, sA0, q, t);
#pragma unroll
  for (int q = 0; q < 4; ++q) stage_q(Bm, n0, ldB, 0, sB0, q, t);
#pragma unroll
  for (int q = 0; q < 4; ++q) stage_q(Bm, n0, ldB, 64, sB1, q, t);
  stage_q(A, m0, ldA, 64, sA1, 0, t);
  stage_q(A, m0, ldA, 64, sA1, 2, t);
  asm volatile("s_waitcnt vmcnt(6)" ::: "memory");
  __builtin_amdgcn_s_barrier();

  auto ktile = [&](int kt, char* cA, char* cB, char* nA) {
    const int k1 = (kt + 1 < NT ? kt + 1 : NT - 1) * 64;
    const int k2 = (kt + 2 < NT ? kt + 2 : NT - 1) * 64;
    bf16x8 bfr[4][2], af[2][2];
#pragma unroll
    for (int nf = 0; nf < 4; ++nf)
#pragma unroll
      for (int ks = 0; ks < 2; ++ks)
        bfr[nf][ks] = lfrag(cB, wc * 64 + nf * 16 + lrow, ks * 64 + kb0);
#pragma unroll
    for (int mf = 0; mf < 2; ++mf)
#pragma unroll
      for (int ks = 0; ks < 2; ++ks)
        af[mf][ks] = lfrag(cA, wr * 128 + mf * 16 + lrow, ks * 64 + kb0);
    stage_q(A, m0, ldA, k1, nA, 1, t);
    stage_q(A, m0, ldA, k1, nA, 3, t);
    __builtin_amdgcn_s_barrier();
    asm volatile("s_waitcnt lgkmcnt(0)" ::: "memory");
    __builtin_amdgcn_sched_barrier(0);
    __builtin_amdgcn_s_setprio(1);
#pragma unroll
    for (int mf = 0; mf < 2; ++mf)
#pragma unroll
      for (int nf = 0; nf < 4; ++nf)
#pragma unroll
        for (int ks = 0; ks < 2; ++ks)
          acc[mf][nf] = __builtin_amdgcn_mfma_f32_16x16x32_bf16(af[mf][ks], bfr[nf][ks], acc[mf][nf], 0, 0, 0);
    __builtin_amdgcn_s_setprio(0);
    __builtin_amdgcn_s_barrier();
#pragma unroll
    for (int q = 1; q < 4; ++q) {
#pragma unroll
      for (int mf = 0; mf < 2; ++mf)
#pragma unroll
        for (int ks = 0; ks < 2; ++ks)
          af[mf][ks] = lfrag(cA, wr * 128 + q * 32 + mf * 16 + lrow, ks * 64 + kb0);
      if (q == 1) { stage_q(Bm, n0, ldB, k2, cB, 0, t); stage_q(Bm, n0, ldB, k2, cB, 1, t); }
      if (q == 2) { stage_q(Bm, n0, ldB, k2, cB, 2, t); stage_q(Bm, n0, ldB, k2, cB, 3, t); }
      if (q == 3) { stage_q(A, m0, ldA, k2, cA, 0, t); stage_q(A, m0, ldA, k2, cA, 2, t);
                    asm volatile("s_waitcnt vmcnt(6)" ::: "memory"); }
      __builtin_amdgcn_s_barrier();
      asm volatile("s_waitcnt lgkmcnt(0)" ::: "memory");
      __builtin_amdgcn_sched_barrier(0);
      __builtin_amdgcn_s_setprio(1);
#pragma unroll
      for (int mf = 0; mf < 2; ++mf)
#pragma unroll
        for (int nf = 0; nf < 4; ++nf)
#pragma unroll
          for (int ks = 0; ks < 2; ++ks)
            acc[2 * q + mf][nf] = __builtin_amdgcn_mfma_f32_16x16x32_bf16(af[mf][ks], bfr[nf][ks], acc[2 * q + mf][nf], 0, 0, 0);
      __builtin_amdgcn_s_setprio(0);
      __builtin_amdgcn_s_barrier();
    }
  };

#pragma unroll 1
  for (int kt = 0; kt < NT; kt += 2) {
    ktile(kt,     sA0, sB0, sA1);
    ktile(kt + 1, sA1, sB1, sA0);
  }
}

// Epilogue LDS staging: per-wave private region, 32 rows x 68 f32 pitch
// (16B-aligned for float4, 4-bank row shift -> balanced). 8*8704B = 68 KiB.
#define EPI_PITCH 68

// ---------------- QKV projection: out = x @ W^T + b -------------------------
// z==0 -> Q row-major, z==1 -> K row-major, z==2 -> V^T [b][h][s] direct.
__global__ __launch_bounds__(512, 2) void qkv_kernel(
    const unsigned short* __restrict__ x, const unsigned short* __restrict__ W3,
    const float* __restrict__ bq, const float* __restrict__ bk, const float* __restrict__ bv,
    unsigned short* __restrict__ Q, unsigned short* __restrict__ K, unsigned short* __restrict__ VT) {
  extern __shared__ char sm[];
  const int z = blockIdx.z;
  const unsigned short* W = W3 + (size_t)z * (H_ * H_);
  const float* bias = (z == 0) ? bq : (z == 1) ? bk : bv;
  const long m0 = (long)blockIdx.y * 256, n0 = (long)blockIdx.x * 256;
  f32x4 acc[8][4] = {};
  gemm8<H_ / 64>(x, H_, m0, W, H_, n0, sm, acc);

  const int lane = threadIdx.x & 63;
  const int wid = threadIdx.x >> 6;
  const int wr = wid >> 2, wc = wid & 3;
  const int g = lane >> 4, c = lane & 15;
  float bb[4];
#pragma unroll
  for (int nf = 0; nf < 4; ++nf) bb[nf] = bias[n0 + wc * 64 + nf * 16 + c];

  if (z == 2) {
    // direct V^T: lane's 4 r-values are 4 consecutive s at fixed col h
#pragma unroll
    for (int mq = 0; mq < 8; ++mq)
#pragma unroll
      for (int nf = 0; nf < 4; ++nf) {
        long col = n0 + wc * 64 + nf * 16 + c;
        long row0 = m0 + wr * 128 + mq * 16 + g * 4;
        long bidx = row0 >> 11;          // batch
        long srow = row0 & (S_ - 1);     // s within batch
        ushort4 o;
        o.x = f2bf(acc[mq][nf][0] + bb[nf]);
        o.y = f2bf(acc[mq][nf][1] + bb[nf]);
        o.z = f2bf(acc[mq][nf][2] + bb[nf]);
        o.w = f2bf(acc[mq][nf][3] + bb[nf]);
        *reinterpret_cast<ushort4*>(VT + bidx * H_ * S_ + col * S_ + srow) = o;
      }
  } else {
    unsigned short* out = (z == 0) ? Q : K;
    float* wbuf = reinterpret_cast<float*>(sm) + wid * (32 * EPI_PITCH);
#pragma unroll
    for (int p = 0; p < 4; ++p) {
#pragma unroll
      for (int h2 = 0; h2 < 2; ++h2)
#pragma unroll
        for (int nf = 0; nf < 4; ++nf)
#pragma unroll
          for (int r = 0; r < 4; ++r)
            wbuf[(h2 * 16 + g * 4 + r) * EPI_PITCH + nf * 16 + c] = acc[p * 2 + h2][nf][r] + bb[nf];
      asm volatile("s_waitcnt lgkmcnt(0)" ::: "memory");
      __builtin_amdgcn_sched_barrier(0);
#pragma unroll
      for (int it = 0; it < 4; ++it) {
        int lr = it * 8 + (lane >> 3);
        long row = m0 + wr * 128 + p * 32 + lr;
        const float* src = wbuf + lr * EPI_PITCH + (lane & 7) * 8;
        float4 v0 = *reinterpret_cast<const float4*>(src);
        float4 v1 = *reinterpret_cast<const float4*>(src + 4);
        short8 o;
        o[0] = f2bf(v0.x); o[1] = f2bf(v0.y); o[2] = f2bf(v0.z); o[3] = f2bf(v0.w);
        o[4] = f2bf(v1.x); o[5] = f2bf(v1.y); o[6] = f2bf(v1.z); o[7] = f2bf(v1.w);
        *reinterpret_cast<short8*>(out + row * H_ + n0 + wc * 64 + (lane & 7) * 8) = o;
      }
    }
  }
}

// ---------------- scores = QK^T -> packed-mask exp -> P(bf16) + rowsum ------
__global__ __launch_bounds__(512, 2) void scores_kernel(
    const unsigned short* __restrict__ Q, const unsigned short* __restrict__ Km,
    const unsigned char* __restrict__ mpkb, unsigned short* __restrict__ P,
    float* __restrict__ rowsum) {
  extern __shared__ char sm[];
  const int b = blockIdx.z;
  const long m0 = (long)blockIdx.y * 256, n0 = (long)blockIdx.x * 256;
  const unsigned short* Qb = Q + (size_t)b * S_ * H_;
  const unsigned short* Kb = Km + (size_t)b * S_ * H_;
  const unsigned char* Mb = mpkb + (size_t)b * S_ * (S_ / 8);
  unsigned short* Pb = P + (size_t)b * S_ * S_;
  f32x4 acc[8][4] = {};
  gemm8<H_ / 64>(Qb, H_, m0, Kb, H_, n0, sm, acc);

  const int lane = threadIdx.x & 63;
  const int wid = threadIdx.x >> 6;
  const int wr = wid >> 2, wc = wid & 3;
  const int g = lane >> 4, c = lane & 15;
  float* wbuf = reinterpret_cast<float*>(sm) + wid * (32 * EPI_PITCH);
#pragma unroll
  for (int p = 0; p < 4; ++p) {
#pragma unroll
    for (int h2 = 0; h2 < 2; ++h2)
#pragma unroll
      for (int nf = 0; nf < 4; ++nf)
#pragma unroll
        for (int r = 0; r < 4; ++r)
          wbuf[(h2 * 16 + g * 4 + r) * EPI_PITCH + nf * 16 + c] = acc[p * 2 + h2][nf][r];
    asm volatile("s_waitcnt lgkmcnt(0)" ::: "memory");
    __builtin_amdgcn_sched_barrier(0);
#pragma unroll
    for (int it = 0; it < 4; ++it) {
      int lr = it * 8 + (lane >> 3);
      long row = m0 + wr * 128 + p * 32 + lr;
      const float* src = wbuf + lr * EPI_PITCH + (lane & 7) * 8;
      float4 v0 = *reinterpret_cast<const float4*>(src);
      float4 v1 = *reinterpret_cast<const float4*>(src + 4);
      unsigned mb = Mb[row * (S_ / 8) + ((n0 + wc * 64) >> 3) + (lane & 7)];
      float pv[8];
      pv[0] = v0.x; pv[1] = v0.y; pv[2] = v0.z; pv[3] = v0.w;
      pv[4] = v1.x; pv[5] = v1.y; pv[6] = v1.z; pv[7] = v1.w;
      float rs = 0.f;
      short8 o;
#pragma unroll
      for (int j = 0; j < 8; ++j) {
        float pj = ((mb >> j) & 1) ? __expf(pv[j] * 0.03125f) : 0.f;
        rs += pj;
        o[j] = (short)f2bf(pj);
      }
      *reinterpret_cast<short8*>(Pb + row * S_ + n0 + wc * 64 + (lane & 7) * 8) = o;
      rs += __shfl_xor(rs, 1, 64);
      rs += __shfl_xor(rs, 2, 64);
      rs += __shfl_xor(rs, 4, 64);
      if ((lane & 7) == 0) atomicAdd(&rowsum[(size_t)b * S_ + row], rs);
    }
  }
}

// ---------------- out = (P V) / rowsum --------------------------------------
__global__ __launch_bounds__(512, 2) void pv_kernel(
    const unsigned short* __restrict__ P, const unsigned short* __restrict__ VT,
    const float* __restrict__ rowsum, float* __restrict__ out) {
  extern __shared__ char sm[];
  const int b = blockIdx.z;
  const long m0 = (long)blockIdx.y * 256, n0 = (long)blockIdx.x * 256;
  const unsigned short* Pb = P + (size_t)b * S_ * S_;
  const unsigned short* VTb = VT + (size_t)b * H_ * S_;
  f32x4 acc[8][4] = {};
  gemm8<S_ / 64>(Pb, S_, m0, VTb, S_, n0, sm, acc);

  const int lane = threadIdx.x & 63;
  const int wid = threadIdx.x >> 6;
  const int wr = wid >> 2, wc = wid & 3;
  const int g = lane >> 4, c = lane & 15;
  float* wbuf = reinterpret_cast<float*>(sm) + wid * (32 * EPI_PITCH);
#pragma unroll
  for (int p = 0; p < 4; ++p) {
#pragma unroll
    for (int h2 = 0; h2 < 2; ++h2)
#pragma unroll
      for (int nf = 0; nf < 4; ++nf)
#pragma unroll
        for (int r = 0; r < 4; ++r)
          wbuf[(h2 * 16 + g * 4 + r) * EPI_PITCH + nf * 16 + c] = acc[p * 2 + h2][nf][r];
    asm volatile("s_waitcnt lgkmcnt(0)" ::: "memory");
    __builtin_amdgcn_sched_barrier(0);
#pragma unroll
    for (int it = 0; it < 8; ++it) {
      int lr = it * 4 + (lane >> 4);
      long row = m0 + wr * 128 + p * 32 + lr;
      float inv = __frcp_rn(rowsum[(size_t)b * S_ + row]);
      const float* src = wbuf + lr * EPI_PITCH + (lane & 15) * 4;
      float4 v = *reinterpret_cast<const float4*>(src);
      float4 o; o.x = v.x * inv; o.y = v.y * inv; o.z = v.z * inv; o.w = v.w * inv;
      *reinterpret_cast<float4*>(out + ((size_t)b * S_ + row) * H_ + n0 + wc * 64 + (lane & 15) * 4) = o;
    }
  }
}

// ---------------- launch ----------------------------------------------------
extern "C" void kernel_launch(void* const* d_in, const int* in_sizes, int n_in,
                              void* d_out, int out_size, void* d_ws, size_t ws_size,
                              hipStream_t stream) {
  const float* x   = (const float*)d_in[0];
  const int* mask  = (const int*)d_in[1];
  const float* Wq  = (const float*)d_in[2];
  const float* bq  = (const float*)d_in[3];
  const float* Wk  = (const float*)d_in[4];
  const float* bk  = (const float*)d_in[5];
  const float* Wv  = (const float*)d_in[6];
  const float* bv  = (const float*)d_in[7];
  float* out = (float*)d_out;

  const size_t MS = (size_t)B_ * S_ * H_;
  unsigned short* xb  = (unsigned short*)d_ws;
  unsigned short* W3  = xb + MS;
  unsigned short* Qb  = W3 + (size_t)3 * H_ * H_;
  unsigned short* Kb  = Qb + MS;
  unsigned short* VTb = Kb + MS;
  unsigned short* Pb  = VTb + MS;
  float* rowsum = (float*)(Pb + (size_t)B_ * S_ * S_);
  unsigned long long* mpk = (unsigned long long*)(rowsum + B_ * S_);

  (void)hipFuncSetAttribute(reinterpret_cast<const void*>(qkv_kernel),
                            hipFuncAttributeMaxDynamicSharedMemorySize, 131072);
  (void)hipFuncSetAttribute(reinterpret_cast<const void*>(scores_kernel),
                            hipFuncAttributeMaxDynamicSharedMemorySize, 131072);
  (void)hipFuncSetAttribute(reinterpret_cast<const void*>(pv_kernel),
                            hipFuncAttributeMaxDynamicSharedMemorySize, 131072);

  hipMemsetAsync(rowsum, 0, (size_t)B_ * S_ * sizeof(float), stream);

  const int NCVT = (int)(MS / 4) + 3 * (H_ * H_ / 4);
  cvt_all_kernel<<<NCVT / 256, 256, 0, stream>>>(x, Wq, Wk, Wv, xb);

  maskpack_kernel<<<(B_ * S_) / 4, 256, 0, stream>>>(mask, mpk);

  qkv_kernel<<<dim3(H_ / 256, (B_ * S_) / 256, 3), 512, 131072, stream>>>(
      xb, W3, bq, bk, bv, Qb, Kb, VTb);

  scores_kernel<<<dim3(S_ / 256, S_ / 256, B_), 512, 131072, stream>>>(
      Qb, Kb, (const unsigned char*)mpk, Pb, rowsum);

  pv_kernel<<<dim3(H_ / 256, S_ / 256, B_), 512, 131072, stream>>>(Pb, VTb, rowsum, out);
}

// Round 4
// 300.230 us; speedup vs baseline: 1.1144x; 1.0662x over previous
//
#include <hip/hip_runtime.h>

#define B_ 4
#define S_ 2048
#define H_ 1024

typedef __bf16 bf16x8 __attribute__((ext_vector_type(8)));
typedef float  f32x4  __attribute__((ext_vector_type(4)));
typedef short  short8 __attribute__((ext_vector_type(8)));

__device__ __forceinline__ unsigned short f2bf(float f) {
  unsigned u = __float_as_uint(f);
  u += 0x7FFF + ((u >> 16) & 1);
  return (unsigned short)(u >> 16);
}

// T1: bijective XCD-chunked remap of the (x,y) plane of one z-slice.
// Requires nwg % 8 == 0 and z-slice size % 8 == 0 (true for all our grids).
__device__ __forceinline__ void xcd_remap(int& bx, int& by, int gx, int nwg) {
  int lin = by * gx + bx;
  int q = nwg >> 3;
  int nl = (lin & 7) * q + (lin >> 3);
  bx = nl % gx; by = nl / gx;
}

// ---------------- fused fp32->bf16 convert (x | Wq | Wk | Wv contiguous) ----
__global__ void cvt_all_kernel(const float* __restrict__ x,
                               const float* __restrict__ wq,
                               const float* __restrict__ wk,
                               const float* __restrict__ wv,
                               unsigned short* __restrict__ dst) {
  int i = blockIdx.x * blockDim.x + threadIdx.x;  // float4 index
  const int NX = (B_ * S_ * H_) / 4;
  const int NW = (H_ * H_) / 4;
  const float* src; int off;
  if (i < NX) { src = x; off = i; }
  else { int j = i - NX; int w = j >> 18; off = j & (NW - 1);
         src = (w == 0) ? wq : (w == 1) ? wk : wv; }
  float4 v = reinterpret_cast<const float4*>(src)[off];
  ushort4 o; o.x = f2bf(v.x); o.y = f2bf(v.y); o.z = f2bf(v.z); o.w = f2bf(v.w);
  reinterpret_cast<ushort4*>(dst)[i] = o;
}

// ---------------- mask -> bit pack (64 MB int32 -> 8 MB bits) --------------
__global__ void maskpack_kernel(const int* __restrict__ mask,
                                unsigned long long* __restrict__ mpk) {
  const int lane = threadIdx.x & 63;
  const long row = (long)blockIdx.x * 4 + (threadIdx.x >> 6);
  const int* mrow = mask + row * S_;
#pragma unroll
  for (int w = 0; w < S_ / 64; ++w) {
    int v = mrow[w * 64 + lane];
    unsigned long long b = __ballot(v != 0);
    if (lane == 0) mpk[row * (S_ / 64) + w] = b;
  }
}

// ---------------- 256xBN 8-phase GEMM core ---------------------------------
// NB=4: BN=256, 8 waves 2Mx4N, per-wave 128x64, acc[8][4] (R1-verified).
// NB=2: BN=128, 8 waves 2Mx4N, per-wave 128x32, acc[8][2].
__device__ __forceinline__ bf16x8 lfrag(const char* base, int row, int kb) {
  return *reinterpret_cast<const bf16x8*>(base + row * 128 + (kb ^ ((row & 7) << 4)));
}

__device__ __forceinline__ void stage_q(const unsigned short* __restrict__ g,
                                        long row0, long ld, int k0e,
                                        char* sbase, int q, int t) {
  int row = q * 64 + (t >> 3);
  int osw = ((t & 7) << 4) ^ ((row & 7) << 4);
  const char* gp = reinterpret_cast<const char*>(g + (row0 + row) * ld + k0e) + osw;
  char* lp = sbase + q * 8192 + ((t >> 6) << 10);  // wave-uniform; HW adds lane*16
  __builtin_amdgcn_global_load_lds((const __attribute__((address_space(1))) void*)gp,
                                   (__attribute__((address_space(3))) void*)lp,
                                   16, 0, 0);
}

template <int NT, int NB>
__device__ __forceinline__ void gemm8(const unsigned short* __restrict__ A, long ldA, long m0,
                                      const unsigned short* __restrict__ Bm, long ldB, long n0,
                                      char* sm, f32x4 (&acc)[8][NB]) {
  const int t = threadIdx.x;
  const int lane = t & 63;
  const int wid = t >> 6;
  const int wr = wid >> 2, wc = wid & 3;
  const int lrow = lane & 15;
  const int kb0 = (lane >> 4) * 16;
  char* sA0 = sm;          char* sB0 = sm + 32768;
  char* sA1 = sm + 65536;  char* sB1 = sm + 98304;

#pragma unroll
  for (int q = 0; q < 4; ++q) stage_q(A, m0, ldA, 0, sA0, q, t);
#pragma unroll
  for (int q = 0; q < NB; ++q) stage_q(Bm, n0, ldB, 0, sB0, q, t);
#pragma unroll
  for (int q = 0; q < NB; ++q) stage_q(Bm, n0, ldB, 64, sB1, q, t);
  stage_q(A, m0, ldA, 64, sA1, 0, t);
  stage_q(A, m0, ldA, 64, sA1, 2, t);
  if constexpr (NB == 4) asm volatile("s_waitcnt vmcnt(6)" ::: "memory");
  else                   asm volatile("s_waitcnt vmcnt(4)" ::: "memory");
  __builtin_amdgcn_s_barrier();

  auto ktile = [&](int kt, char* cA, char* cB, char* nA) {
    const int k1 = (kt + 1 < NT ? kt + 1 : NT - 1) * 64;
    const int k2 = (kt + 2 < NT ? kt + 2 : NT - 1) * 64;
    bf16x8 bfr[NB][2], af[2][2];
    // ---- P1 (q=0): read all B + A rows 0-31; stage A q1,q3(kt+1)->nA
#pragma unroll
    for (int nf = 0; nf < NB; ++nf)
#pragma unroll
      for (int ks = 0; ks < 2; ++ks)
        bfr[nf][ks] = lfrag(cB, wc * (NB * 16) + nf * 16 + lrow, ks * 64 + kb0);
#pragma unroll
    for (int mf = 0; mf < 2; ++mf)
#pragma unroll
      for (int ks = 0; ks < 2; ++ks)
        af[mf][ks] = lfrag(cA, wr * 128 + mf * 16 + lrow, ks * 64 + kb0);
    stage_q(A, m0, ldA, k1, nA, 1, t);
    stage_q(A, m0, ldA, k1, nA, 3, t);
    __builtin_amdgcn_s_barrier();
    asm volatile("s_waitcnt lgkmcnt(0)" ::: "memory");
    __builtin_amdgcn_sched_barrier(0);
    __builtin_amdgcn_s_setprio(1);
#pragma unroll
    for (int mf = 0; mf < 2; ++mf)
#pragma unroll
      for (int nf = 0; nf < NB; ++nf)
#pragma unroll
        for (int ks = 0; ks < 2; ++ks)
          acc[mf][nf] = __builtin_amdgcn_mfma_f32_16x16x32_bf16(af[mf][ks], bfr[nf][ks], acc[mf][nf], 0, 0, 0);
    __builtin_amdgcn_s_setprio(0);
    __builtin_amdgcn_s_barrier();
    // ---- P2..P4 (q=1..3)
#pragma unroll
    for (int q = 1; q < 4; ++q) {
#pragma unroll
      for (int mf = 0; mf < 2; ++mf)
#pragma unroll
        for (int ks = 0; ks < 2; ++ks)
          af[mf][ks] = lfrag(cA, wr * 128 + q * 32 + mf * 16 + lrow, ks * 64 + kb0);
      if (q == 1) { stage_q(Bm, n0, ldB, k2, cB, 0, t); stage_q(Bm, n0, ldB, k2, cB, 1, t); }
      if constexpr (NB == 4) {
        if (q == 2) { stage_q(Bm, n0, ldB, k2, cB, 2, t); stage_q(Bm, n0, ldB, k2, cB, 3, t); }
        if (q == 3) { stage_q(A, m0, ldA, k2, cA, 0, t); stage_q(A, m0, ldA, k2, cA, 2, t);
                      asm volatile("s_waitcnt vmcnt(6)" ::: "memory"); }
      } else {
        if (q == 2) { stage_q(A, m0, ldA, k2, cA, 0, t); stage_q(A, m0, ldA, k2, cA, 2, t); }
        if (q == 3) { asm volatile("s_waitcnt vmcnt(4)" ::: "memory"); }
      }
      __builtin_amdgcn_s_barrier();
      asm volatile("s_waitcnt lgkmcnt(0)" ::: "memory");
      __builtin_amdgcn_sched_barrier(0);
      __builtin_amdgcn_s_setprio(1);
#pragma unroll
      for (int mf = 0; mf < 2; ++mf)
#pragma unroll
        for (int nf = 0; nf < NB; ++nf)
#pragma unroll
          for (int ks = 0; ks < 2; ++ks)
            acc[2 * q + mf][nf] = __builtin_amdgcn_mfma_f32_16x16x32_bf16(af[mf][ks], bfr[nf][ks], acc[2 * q + mf][nf], 0, 0, 0);
      __builtin_amdgcn_s_setprio(0);
      __builtin_amdgcn_s_barrier();
    }
  };

#pragma unroll 1
  for (int kt = 0; kt < NT; kt += 2) {
    ktile(kt,     sA0, sB0, sA1);
    ktile(kt + 1, sA1, sB1, sA0);
  }
  // drain in-flight stages + sync before epilogue reuses LDS (race fix)
  asm volatile("s_waitcnt vmcnt(0)" ::: "memory");
  __syncthreads();
}

#define EPI_PITCH 68

// ---------------- QKV projection: out = x @ W^T + b -------------------------
__global__ __launch_bounds__(512, 2) void qkv_kernel(
    const unsigned short* __restrict__ x, const unsigned short* __restrict__ W3,
    const float* __restrict__ bq, const float* __restrict__ bk, const float* __restrict__ bv,
    unsigned short* __restrict__ Q, unsigned short* __restrict__ K, unsigned short* __restrict__ VT) {
  extern __shared__ char sm[];
  int bx = blockIdx.x, by = blockIdx.y;
  xcd_remap(bx, by, H_ / 256, (H_ / 256) * ((B_ * S_) / 256));
  const int z = blockIdx.z;
  const unsigned short* W = W3 + (size_t)z * (H_ * H_);
  const float* bias = (z == 0) ? bq : (z == 1) ? bk : bv;
  const long m0 = (long)by * 256, n0 = (long)bx * 256;
  f32x4 acc[8][4] = {};
  gemm8<H_ / 64, 4>(x, H_, m0, W, H_, n0, sm, acc);

  const int lane = threadIdx.x & 63;
  const int wid = threadIdx.x >> 6;
  const int wr = wid >> 2, wc = wid & 3;
  const int g = lane >> 4, c = lane & 15;
  float bb[4];
#pragma unroll
  for (int nf = 0; nf < 4; ++nf) bb[nf] = bias[n0 + wc * 64 + nf * 16 + c];

  if (z == 2) {
#pragma unroll
    for (int mq = 0; mq < 8; ++mq)
#pragma unroll
      for (int nf = 0; nf < 4; ++nf) {
        long col = n0 + wc * 64 + nf * 16 + c;
        long row0 = m0 + wr * 128 + mq * 16 + g * 4;
        long bidx = row0 >> 11;
        long srow = row0 & (S_ - 1);
        ushort4 o;
        o.x = f2bf(acc[mq][nf][0] + bb[nf]);
        o.y = f2bf(acc[mq][nf][1] + bb[nf]);
        o.z = f2bf(acc[mq][nf][2] + bb[nf]);
        o.w = f2bf(acc[mq][nf][3] + bb[nf]);
        *reinterpret_cast<ushort4*>(VT + bidx * H_ * S_ + col * S_ + srow) = o;
      }
  } else {
    unsigned short* out = (z == 0) ? Q : K;
    float* wbuf = reinterpret_cast<float*>(sm) + wid * (32 * EPI_PITCH);
#pragma unroll
    for (int p = 0; p < 4; ++p) {
#pragma unroll
      for (int h2 = 0; h2 < 2; ++h2)
#pragma unroll
        for (int nf = 0; nf < 4; ++nf)
#pragma unroll
          for (int r = 0; r < 4; ++r)
            wbuf[(h2 * 16 + g * 4 + r) * EPI_PITCH + nf * 16 + c] = acc[p * 2 + h2][nf][r] + bb[nf];
      asm volatile("s_waitcnt lgkmcnt(0)" ::: "memory");
      __builtin_amdgcn_sched_barrier(0);
#pragma unroll
      for (int it = 0; it < 4; ++it) {
        int lr = it * 8 + (lane >> 3);
        long row = m0 + wr * 128 + p * 32 + lr;
        const float* src = wbuf + lr * EPI_PITCH + (lane & 7) * 8;
        float4 v0 = *reinterpret_cast<const float4*>(src);
        float4 v1 = *reinterpret_cast<const float4*>(src + 4);
        short8 o;
        o[0] = f2bf(v0.x); o[1] = f2bf(v0.y); o[2] = f2bf(v0.z); o[3] = f2bf(v0.w);
        o[4] = f2bf(v1.x); o[5] = f2bf(v1.y); o[6] = f2bf(v1.z); o[7] = f2bf(v1.w);
        *reinterpret_cast<short8*>(out + row * H_ + n0 + wc * 64 + (lane & 7) * 8) = o;
      }
    }
  }
}

// ---------------- scores = QK^T -> packed-mask exp -> P(bf16) + rowsum ------
__global__ __launch_bounds__(512, 2) void scores_kernel(
    const unsigned short* __restrict__ Q, const unsigned short* __restrict__ Km,
    const unsigned char* __restrict__ mpkb, unsigned short* __restrict__ P,
    float* __restrict__ rowsum) {
  extern __shared__ char sm[];
  int bx = blockIdx.x, by = blockIdx.y;
  xcd_remap(bx, by, S_ / 256, (S_ / 256) * (S_ / 256));
  const int b = blockIdx.z;
  const long m0 = (long)by * 256, n0 = (long)bx * 256;
  const unsigned short* Qb = Q + (size_t)b * S_ * H_;
  const unsigned short* Kb = Km + (size_t)b * S_ * H_;
  const unsigned char* Mb = mpkb + (size_t)b * S_ * (S_ / 8);
  unsigned short* Pb = P + (size_t)b * S_ * S_;
  f32x4 acc[8][4] = {};
  gemm8<H_ / 64, 4>(Qb, H_, m0, Kb, H_, n0, sm, acc);

  const int lane = threadIdx.x & 63;
  const int wid = threadIdx.x >> 6;
  const int wr = wid >> 2, wc = wid & 3;
  const int g = lane >> 4, c = lane & 15;
  float* wbuf = reinterpret_cast<float*>(sm) + wid * (32 * EPI_PITCH);
#pragma unroll
  for (int p = 0; p < 4; ++p) {
#pragma unroll
    for (int h2 = 0; h2 < 2; ++h2)
#pragma unroll
      for (int nf = 0; nf < 4; ++nf)
#pragma unroll
        for (int r = 0; r < 4; ++r)
          wbuf[(h2 * 16 + g * 4 + r) * EPI_PITCH + nf * 16 + c] = acc[p * 2 + h2][nf][r];
    asm volatile("s_waitcnt lgkmcnt(0)" ::: "memory");
    __builtin_amdgcn_sched_barrier(0);
#pragma unroll
    for (int it = 0; it < 4; ++it) {
      int lr = it * 8 + (lane >> 3);
      long row = m0 + wr * 128 + p * 32 + lr;
      const float* src = wbuf + lr * EPI_PITCH + (lane & 7) * 8;
      float4 v0 = *reinterpret_cast<const float4*>(src);
      float4 v1 = *reinterpret_cast<const float4*>(src + 4);
      unsigned mb = Mb[row * (S_ / 8) + ((n0 + wc * 64) >> 3) + (lane & 7)];
      float pv[8];
      pv[0] = v0.x; pv[1] = v0.y; pv[2] = v0.z; pv[3] = v0.w;
      pv[4] = v1.x; pv[5] = v1.y; pv[6] = v1.z; pv[7] = v1.w;
      float rs = 0.f;
      short8 o;
#pragma unroll
      for (int j = 0; j < 8; ++j) {
        float pj = ((mb >> j) & 1) ? __expf(pv[j] * 0.03125f) : 0.f;
        rs += pj;
        o[j] = (short)f2bf(pj);
      }
      *reinterpret_cast<short8*>(Pb + row * S_ + n0 + wc * 64 + (lane & 7) * 8) = o;
      rs += __shfl_xor(rs, 1, 64);
      rs += __shfl_xor(rs, 2, 64);
      rs += __shfl_xor(rs, 4, 64);
      if ((lane & 7) == 0) atomicAdd(&rowsum[(size_t)b * S_ + row], rs);
    }
  }
}

// ---------------- out = (P V) / rowsum  (BN=128 variant) --------------------
__global__ __launch_bounds__(512, 2) void pv_kernel(
    const unsigned short* __restrict__ P, const unsigned short* __restrict__ VT,
    const float* __restrict__ rowsum, float* __restrict__ out) {
  extern __shared__ char sm[];
  int bx = blockIdx.x, by = blockIdx.y;
  xcd_remap(bx, by, H_ / 128, (H_ / 128) * (S_ / 256));
  const int b = blockIdx.z;
  const long m0 = (long)by * 256, n0 = (long)bx * 128;
  const unsigned short* Pb = P + (size_t)b * S_ * S_;
  const unsigned short* VTb = VT + (size_t)b * H_ * S_;
  f32x4 acc[8][2] = {};
  gemm8<S_ / 64, 2>(Pb, S_, m0, VTb, S_, n0, sm, acc);

  const int lane = threadIdx.x & 63;
  const int wid = threadIdx.x >> 6;
  const int wr = wid >> 2, wc = wid & 3;
  const int g = lane >> 4, c = lane & 15;
  float* wbuf = reinterpret_cast<float*>(sm) + wid * (32 * 36);
#pragma unroll
  for (int p = 0; p < 4; ++p) {
#pragma unroll
    for (int h2 = 0; h2 < 2; ++h2)
#pragma unroll
      for (int nf = 0; nf < 2; ++nf)
#pragma unroll
        for (int r = 0; r < 4; ++r)
          wbuf[(h2 * 16 + g * 4 + r) * 36 + nf * 16 + c] = acc[p * 2 + h2][nf][r];
    asm volatile("s_waitcnt lgkmcnt(0)" ::: "memory");
    __builtin_amdgcn_sched_barrier(0);
#pragma unroll
    for (int it = 0; it < 4; ++it) {
      int lr = it * 8 + (lane >> 3);
      long row = m0 + wr * 128 + p * 32 + lr;
      float inv = __frcp_rn(rowsum[(size_t)b * S_ + row]);
      const float* src = wbuf + lr * 36 + (lane & 7) * 4;
      float4 v = *reinterpret_cast<const float4*>(src);
      float4 o; o.x = v.x * inv; o.y = v.y * inv; o.z = v.z * inv; o.w = v.w * inv;
      *reinterpret_cast<float4*>(out + ((size_t)b * S_ + row) * H_ + n0 + wc * 32 + (lane & 7) * 4) = o;
    }
  }
}

// ---------------- launch ----------------------------------------------------
extern "C" void kernel_launch(void* const* d_in, const int* in_sizes, int n_in,
                              void* d_out, int out_size, void* d_ws, size_t ws_size,
                              hipStream_t stream) {
  const float* x   = (const float*)d_in[0];
  const int* mask  = (const int*)d_in[1];
  const float* Wq  = (const float*)d_in[2];
  const float* bq  = (const float*)d_in[3];
  const float* Wk  = (const float*)d_in[4];
  const float* bk  = (const float*)d_in[5];
  const float* Wv  = (const float*)d_in[6];
  const float* bv  = (const float*)d_in[7];
  float* out = (float*)d_out;

  const size_t MS = (size_t)B_ * S_ * H_;
  unsigned short* xb  = (unsigned short*)d_ws;
  unsigned short* W3  = xb + MS;
  unsigned short* Qb  = W3 + (size_t)3 * H_ * H_;
  unsigned short* Kb  = Qb + MS;
  unsigned short* VTb = Kb + MS;
  unsigned short* Pb  = VTb + MS;
  float* rowsum = (float*)(Pb + (size_t)B_ * S_ * S_);
  unsigned long long* mpk = (unsigned long long*)(rowsum + B_ * S_);

  (void)hipFuncSetAttribute(reinterpret_cast<const void*>(qkv_kernel),
                            hipFuncAttributeMaxDynamicSharedMemorySize, 131072);
  (void)hipFuncSetAttribute(reinterpret_cast<const void*>(scores_kernel),
                            hipFuncAttributeMaxDynamicSharedMemorySize, 131072);
  (void)hipFuncSetAttribute(reinterpret_cast<const void*>(pv_kernel),
                            hipFuncAttributeMaxDynamicSharedMemorySize, 131072);

  hipMemsetAsync(rowsum, 0, (size_t)B_ * S_ * sizeof(float), stream);

  const int NCVT = (int)(MS / 4) + 3 * (H_ * H_ / 4);
  cvt_all_kernel<<<NCVT / 256, 256, 0, stream>>>(x, Wq, Wk, Wv, xb);

  maskpack_kernel<<<(B_ * S_) / 4, 256, 0, stream>>>(mask, mpk);

  qkv_kernel<<<dim3(H_ / 256, (B_ * S_) / 256, 3), 512, 131072, stream>>>(
      xb, W3, bq, bk, bv, Qb, Kb, VTb);

  scores_kernel<<<dim3(S_ / 256, S_ / 256, B_), 512, 131072, stream>>>(
      Qb, Kb, (const unsigned char*)mpk, Pb, rowsum);

  pv_kernel<<<dim3(H_ / 128, S_ / 256, B_), 512, 131072, stream>>>(Pb, VTb, rowsum, out);
}

// Round 5
// 299.804 us; speedup vs baseline: 1.1159x; 1.0014x over previous
//
#include <hip/hip_runtime.h>

#define B_ 4
#define S_ 2048
#define H_ 1024

typedef __bf16 bf16x8 __attribute__((ext_vector_type(8)));
typedef float  f32x4  __attribute__((ext_vector_type(4)));
typedef short  short8 __attribute__((ext_vector_type(8)));

__device__ __forceinline__ unsigned short f2bf(float f) {
  unsigned u = __float_as_uint(f);
  u += 0x7FFF + ((u >> 16) & 1);
  return (unsigned short)(u >> 16);
}

// ---------------- fused fp32->bf16 convert (x | Wq | Wk | Wv contiguous) ----
__global__ void cvt_all_kernel(const float* __restrict__ x,
                               const float* __restrict__ wq,
                               const float* __restrict__ wk,
                               const float* __restrict__ wv,
                               unsigned short* __restrict__ dst) {
  int i = blockIdx.x * blockDim.x + threadIdx.x;  // float4 index
  const int NX = (B_ * S_ * H_) / 4;
  const int NW = (H_ * H_) / 4;
  const float* src; int off;
  if (i < NX) { src = x; off = i; }
  else { int j = i - NX; int w = j >> 18; off = j & (NW - 1);
         src = (w == 0) ? wq : (w == 1) ? wk : wv; }
  float4 v = reinterpret_cast<const float4*>(src)[off];
  ushort4 o; o.x = f2bf(v.x); o.y = f2bf(v.y); o.z = f2bf(v.z); o.w = f2bf(v.w);
  reinterpret_cast<ushort4*>(dst)[i] = o;
}

// ---------------- mask -> bit pack (64 MB int32 -> 8 MB bits) --------------
__global__ void maskpack_kernel(const int* __restrict__ mask,
                                unsigned long long* __restrict__ mpk) {
  const int lane = threadIdx.x & 63;
  const long row = (long)blockIdx.x * 4 + (threadIdx.x >> 6);
  const int* mrow = mask + row * S_;
#pragma unroll
  for (int w = 0; w < S_ / 64; ++w) {
    int v = mrow[w * 64 + lane];
    unsigned long long b = __ballot(v != 0);
    if (lane == 0) mpk[row * (S_ / 64) + w] = b;
  }
}

// ---------------- 256xBN 8-phase GEMM core ---------------------------------
// NB=4: BN=256, 8 waves 2Mx4N, per-wave 128x64, acc[8][4].
// NB=2: BN=128, 8 waves 2Mx4N, per-wave 128x32, acc[8][2].
__device__ __forceinline__ bf16x8 lfrag(const char* base, int row, int kb) {
  return *reinterpret_cast<const bf16x8*>(base + row * 128 + (kb ^ ((row & 7) << 4)));
}

__device__ __forceinline__ void stage_q(const unsigned short* __restrict__ g,
                                        long row0, long ld, int k0e,
                                        char* sbase, int q, int t) {
  int row = q * 64 + (t >> 3);
  int osw = ((t & 7) << 4) ^ ((row & 7) << 4);
  const char* gp = reinterpret_cast<const char*>(g + (row0 + row) * ld + k0e) + osw;
  char* lp = sbase + q * 8192 + ((t >> 6) << 10);  // wave-uniform; HW adds lane*16
  __builtin_amdgcn_global_load_lds((const __attribute__((address_space(1))) void*)gp,
                                   (__attribute__((address_space(3))) void*)lp,
                                   16, 0, 0);
}

template <int NT, int NB>
__device__ __forceinline__ void gemm8(const unsigned short* __restrict__ A, long ldA, long m0,
                                      const unsigned short* __restrict__ Bm, long ldB, long n0,
                                      char* sm, f32x4 (&acc)[8][NB]) {
  const int t = threadIdx.x;
  const int lane = t & 63;
  const int wid = t >> 6;
  const int wr = wid >> 2, wc = wid & 3;
  const int lrow = lane & 15;
  const int kb0 = (lane >> 4) * 16;
  char* sA0 = sm;          char* sB0 = sm + 32768;
  char* sA1 = sm + 65536;  char* sB1 = sm + 98304;

#pragma unroll
  for (int q = 0; q < 4; ++q) stage_q(A, m0, ldA, 0, sA0, q, t);
#pragma unroll
  for (int q = 0; q < NB; ++q) stage_q(Bm, n0, ldB, 0, sB0, q, t);
#pragma unroll
  for (int q = 0; q < NB; ++q) stage_q(Bm, n0, ldB, 64, sB1, q, t);
  stage_q(A, m0, ldA, 64, sA1, 0, t);
  stage_q(A, m0, ldA, 64, sA1, 2, t);
  if constexpr (NB == 4) asm volatile("s_waitcnt vmcnt(6)" ::: "memory");
  else                   asm volatile("s_waitcnt vmcnt(4)" ::: "memory");
  __builtin_amdgcn_s_barrier();

  auto ktile = [&](int kt, char* cA, char* cB, char* nA) {
    const int k1 = (kt + 1 < NT ? kt + 1 : NT - 1) * 64;
    const int k2 = (kt + 2 < NT ? kt + 2 : NT - 1) * 64;
    bf16x8 bfr[NB][2], af[2][2];
    // ---- P1 (q=0): read all B + A rows 0-31; stage A q1,q3(kt+1)->nA
#pragma unroll
    for (int nf = 0; nf < NB; ++nf)
#pragma unroll
      for (int ks = 0; ks < 2; ++ks)
        bfr[nf][ks] = lfrag(cB, wc * (NB * 16) + nf * 16 + lrow, ks * 64 + kb0);
#pragma unroll
    for (int mf = 0; mf < 2; ++mf)
#pragma unroll
      for (int ks = 0; ks < 2; ++ks)
        af[mf][ks] = lfrag(cA, wr * 128 + mf * 16 + lrow, ks * 64 + kb0);
    stage_q(A, m0, ldA, k1, nA, 1, t);
    stage_q(A, m0, ldA, k1, nA, 3, t);
    __builtin_amdgcn_s_barrier();
    asm volatile("s_waitcnt lgkmcnt(0)" ::: "memory");
    __builtin_amdgcn_sched_barrier(0);
    __builtin_amdgcn_s_setprio(1);
#pragma unroll
    for (int mf = 0; mf < 2; ++mf)
#pragma unroll
      for (int nf = 0; nf < NB; ++nf)
#pragma unroll
        for (int ks = 0; ks < 2; ++ks)
          acc[mf][nf] = __builtin_amdgcn_mfma_f32_16x16x32_bf16(af[mf][ks], bfr[nf][ks], acc[mf][nf], 0, 0, 0);
    __builtin_amdgcn_s_setprio(0);
    __builtin_amdgcn_s_barrier();
    // ---- P2..P4 (q=1..3)
#pragma unroll
    for (int q = 1; q < 4; ++q) {
#pragma unroll
      for (int mf = 0; mf < 2; ++mf)
#pragma unroll
        for (int ks = 0; ks < 2; ++ks)
          af[mf][ks] = lfrag(cA, wr * 128 + q * 32 + mf * 16 + lrow, ks * 64 + kb0);
      if (q == 1) { stage_q(Bm, n0, ldB, k2, cB, 0, t); stage_q(Bm, n0, ldB, k2, cB, 1, t); }
      if constexpr (NB == 4) {
        if (q == 2) { stage_q(Bm, n0, ldB, k2, cB, 2, t); stage_q(Bm, n0, ldB, k2, cB, 3, t); }
        if (q == 3) { stage_q(A, m0, ldA, k2, cA, 0, t); stage_q(A, m0, ldA, k2, cA, 2, t);
                      asm volatile("s_waitcnt vmcnt(6)" ::: "memory"); }
      } else {
        if (q == 2) { stage_q(A, m0, ldA, k2, cA, 0, t); stage_q(A, m0, ldA, k2, cA, 2, t); }
        if (q == 3) { asm volatile("s_waitcnt vmcnt(4)" ::: "memory"); }
      }
      __builtin_amdgcn_s_barrier();
      asm volatile("s_waitcnt lgkmcnt(0)" ::: "memory");
      __builtin_amdgcn_sched_barrier(0);
      __builtin_amdgcn_s_setprio(1);
#pragma unroll
      for (int mf = 0; mf < 2; ++mf)
#pragma unroll
        for (int nf = 0; nf < NB; ++nf)
#pragma unroll
          for (int ks = 0; ks < 2; ++ks)
            acc[2 * q + mf][nf] = __builtin_amdgcn_mfma_f32_16x16x32_bf16(af[mf][ks], bfr[nf][ks], acc[2 * q + mf][nf], 0, 0, 0);
      __builtin_amdgcn_s_setprio(0);
      __builtin_amdgcn_s_barrier();
    }
  };

#pragma unroll 1
  for (int kt = 0; kt < NT; kt += 2) {
    ktile(kt,     sA0, sB0, sA1);
    ktile(kt + 1, sA1, sB1, sA0);
  }
  // drain in-flight stages + sync before epilogue reuses LDS
  asm volatile("s_waitcnt vmcnt(0)" ::: "memory");
  __syncthreads();
}

#define EPI_PITCH 68

// ---------------- QKV projection (NB=2): out = x @ W^T + b ------------------
// Grid (8,32,3) = 768 blocks = exactly 3 full rounds on 256 CUs.
// XCD remap: XCD c (= id%8) gets by in [4c,4c+4) for all bx,z ->
// computes Q/K/V rows [1024c, 1024c+1024) (aligned with scores' consumer band).
__global__ __launch_bounds__(512, 2) void qkv_kernel(
    const unsigned short* __restrict__ x, const unsigned short* __restrict__ W3,
    const float* __restrict__ bq, const float* __restrict__ bk, const float* __restrict__ bv,
    unsigned short* __restrict__ Q, unsigned short* __restrict__ K, unsigned short* __restrict__ VT) {
  extern __shared__ char sm[];
  int id = blockIdx.x + 8 * (blockIdx.y + 32 * blockIdx.z);  // 0..767
  int c8 = id & 7, j = id >> 3;                              // XCD key, 0..95
  int z  = j >> 5;                                           // 0..2
  int by = 4 * c8 + (j & 3);                                 // 0..31
  int bx = (j >> 2) & 7;                                     // 0..7
  const unsigned short* W = W3 + (size_t)z * (H_ * H_);
  const float* bias = (z == 0) ? bq : (z == 1) ? bk : bv;
  const long m0 = (long)by * 256, n0 = (long)bx * 128;
  f32x4 acc[8][2] = {};
  gemm8<H_ / 64, 2>(x, H_, m0, W, H_, n0, sm, acc);

  const int lane = threadIdx.x & 63;
  const int wid = threadIdx.x >> 6;
  const int wr = wid >> 2, wc = wid & 3;
  const int g = lane >> 4, c = lane & 15;
  float bb[2];
#pragma unroll
  for (int nf = 0; nf < 2; ++nf) bb[nf] = bias[n0 + wc * 32 + nf * 16 + c];

  if (z == 2) {
    // direct V^T: lane's 4 r-values are 4 consecutive s at fixed col h
#pragma unroll
    for (int mq = 0; mq < 8; ++mq)
#pragma unroll
      for (int nf = 0; nf < 2; ++nf) {
        long col = n0 + wc * 32 + nf * 16 + c;
        long row0 = m0 + wr * 128 + mq * 16 + g * 4;
        long bidx = row0 >> 11;
        long srow = row0 & (S_ - 1);
        ushort4 o;
        o.x = f2bf(acc[mq][nf][0] + bb[nf]);
        o.y = f2bf(acc[mq][nf][1] + bb[nf]);
        o.z = f2bf(acc[mq][nf][2] + bb[nf]);
        o.w = f2bf(acc[mq][nf][3] + bb[nf]);
        *reinterpret_cast<ushort4*>(VT + bidx * H_ * S_ + col * S_ + srow) = o;
      }
  } else {
    unsigned short* out = (z == 0) ? Q : K;
    float* wbuf = reinterpret_cast<float*>(sm) + wid * (32 * 36);
#pragma unroll
    for (int p = 0; p < 4; ++p) {
#pragma unroll
      for (int h2 = 0; h2 < 2; ++h2)
#pragma unroll
        for (int nf = 0; nf < 2; ++nf)
#pragma unroll
          for (int r = 0; r < 4; ++r)
            wbuf[(h2 * 16 + g * 4 + r) * 36 + nf * 16 + c] = acc[p * 2 + h2][nf][r] + bb[nf];
      asm volatile("s_waitcnt lgkmcnt(0)" ::: "memory");
      __builtin_amdgcn_sched_barrier(0);
#pragma unroll
      for (int it = 0; it < 4; ++it) {
        int lr = it * 8 + (lane >> 3);
        long row = m0 + wr * 128 + p * 32 + lr;
        const float* src = wbuf + lr * 36 + (lane & 7) * 4;
        float4 v = *reinterpret_cast<const float4*>(src);
        ushort4 o;
        o.x = f2bf(v.x); o.y = f2bf(v.y); o.z = f2bf(v.z); o.w = f2bf(v.w);
        *reinterpret_cast<ushort4*>(out + row * H_ + n0 + wc * 32 + (lane & 7) * 4) = o;
      }
    }
  }
}

// ---------------- scores = QK^T -> packed-mask exp -> P(bf16) + rowsum ------
// Grid (8,8,4) = 256 blocks. XCD c: batch c>>1, Q-row band 4*(c&1)*256..,
// exactly the band qkv XCD c produced.
__global__ __launch_bounds__(512, 2) void scores_kernel(
    const unsigned short* __restrict__ Q, const unsigned short* __restrict__ Km,
    const unsigned char* __restrict__ mpkb, unsigned short* __restrict__ P,
    float* __restrict__ rowsum) {
  extern __shared__ char sm[];
  int id = blockIdx.x + 8 * (blockIdx.y + 8 * blockIdx.z);  // 0..255
  int c8 = id & 7, j = id >> 3;                             // XCD key, 0..31
  int b  = c8 >> 1;
  int by = 4 * (c8 & 1) + (j & 3);
  int bx = j >> 2;                                          // 0..7
  const long m0 = (long)by * 256, n0 = (long)bx * 256;
  const unsigned short* Qb = Q + (size_t)b * S_ * H_;
  const unsigned short* Kb = Km + (size_t)b * S_ * H_;
  const unsigned char* Mb = mpkb + (size_t)b * S_ * (S_ / 8);
  unsigned short* Pb = P + (size_t)b * S_ * S_;
  f32x4 acc[8][4] = {};
  gemm8<H_ / 64, 4>(Qb, H_, m0, Kb, H_, n0, sm, acc);

  const int lane = threadIdx.x & 63;
  const int wid = threadIdx.x >> 6;
  const int wr = wid >> 2, wc = wid & 3;
  const int g = lane >> 4, c = lane & 15;
  float* wbuf = reinterpret_cast<float*>(sm) + wid * (32 * EPI_PITCH);
#pragma unroll
  for (int p = 0; p < 4; ++p) {
#pragma unroll
    for (int h2 = 0; h2 < 2; ++h2)
#pragma unroll
      for (int nf = 0; nf < 4; ++nf)
#pragma unroll
        for (int r = 0; r < 4; ++r)
          wbuf[(h2 * 16 + g * 4 + r) * EPI_PITCH + nf * 16 + c] = acc[p * 2 + h2][nf][r];
    asm volatile("s_waitcnt lgkmcnt(0)" ::: "memory");
    __builtin_amdgcn_sched_barrier(0);
#pragma unroll
    for (int it = 0; it < 4; ++it) {
      int lr = it * 8 + (lane >> 3);
      long row = m0 + wr * 128 + p * 32 + lr;
      const float* src = wbuf + lr * EPI_PITCH + (lane & 7) * 8;
      float4 v0 = *reinterpret_cast<const float4*>(src);
      float4 v1 = *reinterpret_cast<const float4*>(src + 4);
      unsigned mb = Mb[row * (S_ / 8) + ((n0 + wc * 64) >> 3) + (lane & 7)];
      float pv[8];
      pv[0] = v0.x; pv[1] = v0.y; pv[2] = v0.z; pv[3] = v0.w;
      pv[4] = v1.x; pv[5] = v1.y; pv[6] = v1.z; pv[7] = v1.w;
      float rs = 0.f;
      short8 o;
#pragma unroll
      for (int jj = 0; jj < 8; ++jj) {
        float pj = ((mb >> jj) & 1) ? __expf(pv[jj] * 0.03125f) : 0.f;
        rs += pj;
        o[jj] = (short)f2bf(pj);
      }
      *reinterpret_cast<short8*>(Pb + row * S_ + n0 + wc * 64 + (lane & 7) * 8) = o;
      rs += __shfl_xor(rs, 1, 64);
      rs += __shfl_xor(rs, 2, 64);
      rs += __shfl_xor(rs, 4, 64);
      if ((lane & 7) == 0) atomicAdd(&rowsum[(size_t)b * S_ + row], rs);
    }
  }
}

// ---------------- out = (P V) / rowsum  (BN=128) ----------------------------
// Grid (8,8,4) = 256 blocks. XCD c: same (batch, P m-band) scores XCD c wrote.
__global__ __launch_bounds__(512, 2) void pv_kernel(
    const unsigned short* __restrict__ P, const unsigned short* __restrict__ VT,
    const float* __restrict__ rowsum, float* __restrict__ out) {
  extern __shared__ char sm[];
  int id = blockIdx.x + 8 * (blockIdx.y + 8 * blockIdx.z);  // 0..255
  int c8 = id & 7, j = id >> 3;
  int b  = c8 >> 1;
  int by = 4 * (c8 & 1) + (j & 3);
  int bx = j >> 2;                                          // 0..7
  const long m0 = (long)by * 256, n0 = (long)bx * 128;
  const unsigned short* Pb = P + (size_t)b * S_ * S_;
  const unsigned short* VTb = VT + (size_t)b * H_ * S_;
  f32x4 acc[8][2] = {};
  gemm8<S_ / 64, 2>(Pb, S_, m0, VTb, S_, n0, sm, acc);

  const int lane = threadIdx.x & 63;
  const int wid = threadIdx.x >> 6;
  const int wr = wid >> 2, wc = wid & 3;
  const int g = lane >> 4, c = lane & 15;
  float* wbuf = reinterpret_cast<float*>(sm) + wid * (32 * 36);
#pragma unroll
  for (int p = 0; p < 4; ++p) {
#pragma unroll
    for (int h2 = 0; h2 < 2; ++h2)
#pragma unroll
      for (int nf = 0; nf < 2; ++nf)
#pragma unroll
        for (int r = 0; r < 4; ++r)
          wbuf[(h2 * 16 + g * 4 + r) * 36 + nf * 16 + c] = acc[p * 2 + h2][nf][r];
    asm volatile("s_waitcnt lgkmcnt(0)" ::: "memory");
    __builtin_amdgcn_sched_barrier(0);
#pragma unroll
    for (int it = 0; it < 4; ++it) {
      int lr = it * 8 + (lane >> 3);
      long row = m0 + wr * 128 + p * 32 + lr;
      float inv = __frcp_rn(rowsum[(size_t)b * S_ + row]);
      const float* src = wbuf + lr * 36 + (lane & 7) * 4;
      float4 v = *reinterpret_cast<const float4*>(src);
      float4 o; o.x = v.x * inv; o.y = v.y * inv; o.z = v.z * inv; o.w = v.w * inv;
      *reinterpret_cast<float4*>(out + ((size_t)b * S_ + row) * H_ + n0 + wc * 32 + (lane & 7) * 4) = o;
    }
  }
}

// ---------------- launch ----------------------------------------------------
extern "C" void kernel_launch(void* const* d_in, const int* in_sizes, int n_in,
                              void* d_out, int out_size, void* d_ws, size_t ws_size,
                              hipStream_t stream) {
  const float* x   = (const float*)d_in[0];
  const int* mask  = (const int*)d_in[1];
  const float* Wq  = (const float*)d_in[2];
  const float* bq  = (const float*)d_in[3];
  const float* Wk  = (const float*)d_in[4];
  const float* bk  = (const float*)d_in[5];
  const float* Wv  = (const float*)d_in[6];
  const float* bv  = (const float*)d_in[7];
  float* out = (float*)d_out;

  const size_t MS = (size_t)B_ * S_ * H_;
  unsigned short* xb  = (unsigned short*)d_ws;
  unsigned short* W3  = xb + MS;
  unsigned short* Qb  = W3 + (size_t)3 * H_ * H_;
  unsigned short* Kb  = Qb + MS;
  unsigned short* VTb = Kb + MS;
  unsigned short* Pb  = VTb + MS;
  float* rowsum = (float*)(Pb + (size_t)B_ * S_ * S_);
  unsigned long long* mpk = (unsigned long long*)(rowsum + B_ * S_);

  (void)hipFuncSetAttribute(reinterpret_cast<const void*>(qkv_kernel),
                            hipFuncAttributeMaxDynamicSharedMemorySize, 131072);
  (void)hipFuncSetAttribute(reinterpret_cast<const void*>(scores_kernel),
                            hipFuncAttributeMaxDynamicSharedMemorySize, 131072);
  (void)hipFuncSetAttribute(reinterpret_cast<const void*>(pv_kernel),
                            hipFuncAttributeMaxDynamicSharedMemorySize, 131072);

  hipMemsetAsync(rowsum, 0, (size_t)B_ * S_ * sizeof(float), stream);

  const int NCVT = (int)(MS / 4) + 3 * (H_ * H_ / 4);
  cvt_all_kernel<<<NCVT / 256, 256, 0, stream>>>(x, Wq, Wk, Wv, xb);

  maskpack_kernel<<<(B_ * S_) / 4, 256, 0, stream>>>(mask, mpk);

  qkv_kernel<<<dim3(8, 32, 3), 512, 131072, stream>>>(
      xb, W3, bq, bk, bv, Qb, Kb, VTb);

  scores_kernel<<<dim3(8, 8, 4), 512, 131072, stream>>>(
      Qb, Kb, (const unsigned char*)mpk, Pb, rowsum);

  pv_kernel<<<dim3(8, 8, 4), 512, 131072, stream>>>(Pb, VTb, rowsum, out);
}